// Round 10
// baseline (68.202 us; speedup 1.0000x reference)
//
#include <hip/hip_runtime.h>
#include <math.h>

// Problem constants (from reference setup_inputs)
constexpr int B = 8, N = 2048, H = 512, M = 96, S = 16;
constexpr int E = 256, D = 64, R = 5, MAXD = 600;
constexpr int NZ = 64;            // n-splits for sent max partial
constexpr int NCHUNK = N / NZ;    // 32
constexpr int MTA = 6;            // mentions per fused gemm block (96/6=16 groups)
constexpr int MT4 = 8;            // m-rows per final-max tile
constexpr float NEG_INF = -1e10f;

constexpr int A_GEMM = 2 * B * (M / MTA);   // 256 fused entity blocks
constexpr int A_SENT = 256;                 // sent-partial blocks (2 z each)
constexpr int A_DIST = MAXD / 4;            // 150
constexpr int A_GRID = A_GEMM + A_SENT + A_DIST;   // 662

__device__ inline void atomicMaxFloat(float* addr, float val) {
    int* ai = (int*)addr;
    int old = *ai;
    while (__int_as_float(old) < val) {
        int assumed = old;
        old = atomicCAS(ai, assumed, __float_as_int(val));
        if (old == assumed) break;
    }
}

// ===========================================================================
// Kernel A: fused pool+GEMM+tanh+proj | sent-partial max | dist table | out init
// ===========================================================================
__global__ __launch_bounds__(256)
void kA(const float* __restrict__ node,
        const int* __restrict__ cmap, const float* __restrict__ cmask,
        const int* __restrict__ dmap, const float* __restrict__ dmask,
        const float* __restrict__ Wc, const float* __restrict__ bc,
        const float* __restrict__ Wd, const float* __restrict__ bd,
        const float* __restrict__ Wsc, const float* __restrict__ emb,
        float* __restrict__ part, float* __restrict__ sAB,
        float* __restrict__ validAB, float* __restrict__ sD,
        float* __restrict__ out) {
    const int blk = blockIdx.x;
    const int t = threadIdx.x;

    if (blk == 0 && t < B * R) out[t] = NEG_INF;   // init for kB's atomicMax

    if (blk < A_GEMM) {
        // ---- fused: gather/pool 6 mentions -> GEMM (h-split waves) -> tanh -> proj
        int j  = blk;
        int mg = j % (M / MTA);
        int b  = (j / (M / MTA)) % B;
        int z  = j / ((M / MTA) * B);
        const float* W    = z ? Wd : Wc;
        const float* bias = z ? bd : bc;
        const int*   map  = z ? dmap  : cmap;
        const float* mask = z ? dmask : cmask;
        int scoff = z ? E : 0;

        __shared__ float pooled[MTA][H];       // 12 KB
        __shared__ float red4[4][MTA][E];      // 24 KB (per-wave partial dots)
        __shared__ int   smap[MTA][S];
        __shared__ float smask[MTA][S];

        if (t < MTA * S) {
            int mi = t >> 4, s = t & 15;
            size_t off = ((size_t)b * M + mg * MTA + mi) * S + s;
            smap[mi][s]  = map[off];
            smask[mi][s] = mask[off];
        }
        __syncthreads();

        // pool: 2 mentions per pass, thread = (mi-half, float4 slot of H)
        #pragma unroll
        for (int pass = 0; pass < MTA / 2; ++pass) {
            int mi = pass * 2 + (t >> 7);
            int tt = t & 127;    // float4 index over H
            float4 a = make_float4(0.f, 0.f, 0.f, 0.f);
            #pragma unroll
            for (int s = 0; s < S; ++s) {
                float mk = smask[mi][s];
                const float4 v = reinterpret_cast<const float4*>(
                    node + ((size_t)b * N + smap[mi][s]) * H)[tt];
                a.x += mk * v.x; a.y += mk * v.y;
                a.z += mk * v.z; a.w += mk * v.w;
            }
            reinterpret_cast<float4*>(&pooled[mi][0])[tt] = a;
        }
        if (t < MTA) {
            float ms = 0.f;
            #pragma unroll
            for (int s = 0; s < S; ++s) ms += smask[t][s];
            validAB[((size_t)z * B + b) * M + mg * MTA + t] = (ms > 0.f) ? 1.f : 0.f;
        }
        __syncthreads();

        // GEMM: wave = h-chunk (128 rows), lane = e-quad, 6 mentions in regs.
        const int eq = t & 63;       // e-quad: e = 4*eq .. 4*eq+3
        const int w  = t >> 6;       // h-chunk index
        const int h0 = w * (H / 4);
        const float4* W4 = reinterpret_cast<const float4*>(W) + eq;
        float4 acc[MTA];
        #pragma unroll
        for (int mi = 0; mi < MTA; ++mi) acc[mi] = make_float4(0.f, 0.f, 0.f, 0.f);

        #pragma unroll 4
        for (int hh4 = 0; hh4 < (H / 4) / 4; ++hh4) {   // 32 iters of 4 h's
            int h = h0 + hh4 * 4;
            const float4 w0 = W4[(size_t)(h + 0) * (E / 4)];
            const float4 w1 = W4[(size_t)(h + 1) * (E / 4)];
            const float4 w2 = W4[(size_t)(h + 2) * (E / 4)];
            const float4 w3 = W4[(size_t)(h + 3) * (E / 4)];
            #pragma unroll
            for (int mi = 0; mi < MTA; ++mi) {
                const float4 p = *reinterpret_cast<const float4*>(&pooled[mi][h]);
                acc[mi].x += p.x*w0.x + p.y*w1.x + p.z*w2.x + p.w*w3.x;
                acc[mi].y += p.x*w0.y + p.y*w1.y + p.z*w2.y + p.w*w3.y;
                acc[mi].z += p.x*w0.z + p.y*w1.z + p.z*w2.z + p.w*w3.z;
                acc[mi].w += p.x*w0.w + p.y*w1.w + p.z*w2.w + p.w*w3.w;
            }
        }
        #pragma unroll
        for (int mi = 0; mi < MTA; ++mi)
            reinterpret_cast<float4*>(&red4[w][mi][0])[eq] = acc[mi];
        __syncthreads();

        // waves finish mentions mi = w, w+4: sum 4 partials, tanh, rank-5 proj
        for (int mi = w; mi < MTA; mi += 4) {
            float4 dv = reinterpret_cast<const float4*>(&red4[0][mi][0])[eq];
            #pragma unroll
            for (int ww = 1; ww < 4; ++ww) {
                float4 v = reinterpret_cast<const float4*>(&red4[ww][mi][0])[eq];
                dv.x += v.x; dv.y += v.y; dv.z += v.z; dv.w += v.w;
            }
            float4 bv = reinterpret_cast<const float4*>(bias)[eq];
            float v0 = tanhf(dv.x + bv.x);
            float v1 = tanhf(dv.y + bv.y);
            float v2 = tanhf(dv.z + bv.z);
            float v3 = tanhf(dv.w + bv.w);

            int e0 = scoff + 4 * eq;
            float p[R];
            #pragma unroll
            for (int r = 0; r < R; ++r) {
                p[r] = v0 * Wsc[(size_t)(e0 + 0) * R + r] + v1 * Wsc[(size_t)(e0 + 1) * R + r]
                     + v2 * Wsc[(size_t)(e0 + 2) * R + r] + v3 * Wsc[(size_t)(e0 + 3) * R + r];
            }
            #pragma unroll
            for (int r = 0; r < R; ++r) {
                for (int off = 32; off; off >>= 1) p[r] += __shfl_down(p[r], off, 64);
            }
            if (eq == 0) {
                size_t row = ((size_t)z * B + b) * M + mg * MTA + mi;
                #pragma unroll
                for (int r = 0; r < R; ++r) sAB[row * R + r] = p[r];
            }
        }
    } else if (blk < A_GEMM + A_SENT) {
        // ---- sent partial max: block covers (b, 2 z-chunks) ----
        int sb = blk - A_GEMM;
        int b = sb >> 5;
        int z = ((sb & 31) << 1) + (t >> 7);
        int tt = t & 127;   // float4 index over H
        const float4* p = reinterpret_cast<const float4*>(
            node + ((size_t)b * N + (size_t)z * NCHUNK) * H) + tt;
        float4 mx = p[0];
        #pragma unroll
        for (int n = 1; n < NCHUNK; ++n) {
            float4 v = p[(size_t)n * (H / 4)];
            mx.x = fmaxf(mx.x, v.x); mx.y = fmaxf(mx.y, v.y);
            mx.z = fmaxf(mx.z, v.z); mx.w = fmaxf(mx.w, v.w);
        }
        reinterpret_cast<float4*>(part + ((size_t)z * B + b) * H)[tt] = mx;
    } else {
        // ---- distance table: 4 distances per block, one wave each ----
        int d = (blk - A_GEMM - A_SENT) * 4 + (t >> 6);
        int k = t & 63;
        float v = emb[(size_t)d * D + k];
        #pragma unroll
        for (int r = 0; r < R; ++r) {
            float p = v * Wsc[(size_t)(2 * E + k) * R + r];
            for (int off = 32; off; off >>= 1) p += __shfl_down(p, off, 64);
            if (k == 0) sD[d * R + r] = p;
        }
    }
}

// ===========================================================================
// Kernel B: per (b, 8-mention tile): sent finish + sS dot in-block, pair max,
// atomicMax into out.  grid (12 * 8 = 96), block 256.
// ===========================================================================
__global__ void kB(const float* __restrict__ part, const float* __restrict__ Wsc,
                   const float* __restrict__ bsc,
                   const int* __restrict__ distance,
                   const float* __restrict__ sAB, const float* __restrict__ validAB,
                   const float* __restrict__ sD, float* __restrict__ out) {
    const int g = blockIdx.x % (M / MT4);
    const int b = blockIdx.x / (M / MT4);
    const int t = threadIdx.x;

    __shared__ float sent[H];          // 2 KB
    __shared__ float red[R][4];
    __shared__ float sSb[R];
    __shared__ float lB[M * R];        // 1.9 KB
    __shared__ float lD[MAXD * R];     // 12 KB
    __shared__ float lA[MT4 * R];
    __shared__ float lvA[MT4], lvB[M];

    // ---- sent max over z-partials (b-slice of part, L2-shared by 12 blocks) ----
    for (int h = t; h < H; h += 256) {
        float mx = -INFINITY;
        #pragma unroll 8
        for (int z = 0; z < NZ; ++z) mx = fmaxf(mx, part[((size_t)z * B + b) * H + h]);
        sent[h] = mx;
    }
    __syncthreads();

    // ---- sS[r] = sent . Wsc[576:1088] + bsc ----
    float acc[R] = {};
    for (int h = t; h < H; h += 256) {
        float v = sent[h];
        const float* w = Wsc + (size_t)(2 * E + D + h) * R;
        #pragma unroll
        for (int r = 0; r < R; ++r) acc[r] += v * w[r];
    }
    int wave = t >> 6, lane = t & 63;
    #pragma unroll
    for (int r = 0; r < R; ++r) {
        float v = acc[r];
        for (int off = 32; off; off >>= 1) v += __shfl_down(v, off, 64);
        if (lane == 0) red[r][wave] = v;
    }
    __syncthreads();
    if (t < R) sSb[t] = red[t][0] + red[t][1] + red[t][2] + red[t][3] + bsc[t];
    __syncthreads();

    // ---- stage tile operands ----
    for (int i = t; i < M * R; i += 256) lB[i] = sAB[((size_t)(B + b)) * M * R + i];
    for (int i = t; i < MAXD * R; i += 256) lD[i] = sD[i];
    if (t < MT4 * R) lA[t] = sAB[((size_t)b * M + g * MT4) * R + t] + sSb[t % R];
    if (t < MT4) lvA[t] = validAB[(size_t)b * M + g * MT4 + t];
    for (int i = t; i < M; i += 256) lvB[i] = validAB[((size_t)B + b) * M + i];
    __syncthreads();

    // ---- pair max over 8 x 96 ----
    float mx[R];
    #pragma unroll
    for (int r = 0; r < R; ++r) mx[r] = NEG_INF;

    #pragma unroll
    for (int it = 0; it < (MT4 * M) / 256; ++it) {
        int idx = it * 256 + t;           // [0, 768)
        int mi = idx / M, n = idx % M;
        int dist = distance[((size_t)b * M + g * MT4 + mi) * M + n];
        if (lvA[mi] > 0.f && lvB[n] > 0.f && dist >= 0 /*DIST_THRESH*/) {
            #pragma unroll
            for (int r = 0; r < R; ++r)
                mx[r] = fmaxf(mx[r], lA[mi * R + r] + lB[n * R + r] + lD[dist * R + r]);
        }
    }
    #pragma unroll
    for (int r = 0; r < R; ++r) {
        float v = mx[r];
        for (int off = 32; off; off >>= 1) v = fmaxf(v, __shfl_down(v, off, 64));
        if (lane == 0) red[r][wave] = v;
    }
    __syncthreads();
    if (t < R) {
        float v = fmaxf(fmaxf(red[t][0], red[t][1]), fmaxf(red[t][2], red[t][3]));
        atomicMaxFloat(out + b * R + t, v);
    }
}

// ---------------------------------------------------------------------------
extern "C" void kernel_launch(void* const* d_in, const int* in_sizes, int n_in,
                              void* d_out, int out_size, void* d_ws, size_t ws_size,
                              hipStream_t stream) {
    const float* node     = (const float*)d_in[0];
    const int*   cmap     = (const int*)  d_in[1];
    const float* cmask    = (const float*)d_in[2];
    const int*   dmap     = (const int*)  d_in[3];
    const float* dmask    = (const float*)d_in[4];
    const int*   distance = (const int*)  d_in[5];
    const float* Wc       = (const float*)d_in[6];
    const float* bc       = (const float*)d_in[7];
    const float* Wd       = (const float*)d_in[8];
    const float* bd       = (const float*)d_in[9];
    const float* Wsc      = (const float*)d_in[10];
    const float* bsc      = (const float*)d_in[11];
    const float* emb      = (const float*)d_in[12];
    float* out = (float*)d_out;

    // workspace layout (floats): total ~1.1 MB
    float* ws      = (float*)d_ws;
    float* part    = ws;                             // NZ*B*H   = 262144
    float* sAB     = part + (size_t)NZ * B * H;      // 2*B*M*R  = 7680
    float* validAB = sAB + 2 * B * M * R;            // 2*B*M    = 1536
    float* sD      = validAB + 2 * B * M;            // MAXD*R   = 3000

    hipLaunchKernelGGL(kA, dim3(A_GRID), dim3(256), 0, stream,
                       node, cmap, cmask, dmap, dmask, Wc, bc, Wd, bd, Wsc, emb,
                       part, sAB, validAB, sD, out);
    hipLaunchKernelGGL(kB, dim3((M / MT4) * B), dim3(256), 0, stream,
                       part, Wsc, bsc, distance, sAB, validAB, sD, out);
}